// Round 7
// baseline (271.831 us; speedup 1.0000x reference)
//
#include <hip/hip_runtime.h>
#include <stdint.h>

#define BS 7
#define HM 50
#define WM 50
#define HH 56
#define WW 56
#define PLANE_IN  (HM * WM)   // 2500
#define PLANE_OUT (HH * WW)   // 3136
#define NPLANES   (64 * 256)  // 16384
#define COUNT_M   51380224.0f // 64*256*56*56 = 49 * 2^20, exact in fp32
#define K2_REPS   5           // DIAGNOSTIC: x5 internal repeat so the K2
                              // dispatch (~5x its true dur) displaces the
                              // 117us harness fills from rocprof's top-5 and
                              // we finally get per-kernel counters.

typedef unsigned long long u64;

// ===== R2 configuration verbatim (best known: 110 us) except K2's rep loop =====

// Kernel 1: per-plane 7x7 dilation, 16384 blocks, LDS atomicOr seeds,
// per-plane count via plain store (no global atomics).
__global__ __launch_bounds__(256) void dropblock_dilate(
    const float* __restrict__ mask,
    u64* __restrict__ bitmap,
    unsigned* __restrict__ counts)
{
    __shared__ u64 rowbits[HM];
    __shared__ u64 rowdil[HM];
    __shared__ unsigned cnt;

    const int tid = threadIdx.x;
    const int p = blockIdx.x;

    if (tid < HM) rowbits[tid] = 0ULL;
    if (tid == 0) cnt = 0;
    __syncthreads();

    const float4* mp = reinterpret_cast<const float4*>(mask + (size_t)p * PLANE_IN);
    for (int j = tid; j < PLANE_IN / 4; j += 256) {  // 625 float4, no tail
        float4 v = mp[j];
        const int e = 4 * j;
        float vv[4] = {v.x, v.y, v.z, v.w};
#pragma unroll
        for (int k = 0; k < 4; ++k) {
            if (vv[k] != 0.0f) {
                int idx = e + k;
                int r = idx / WM;
                int w = idx - r * WM;
                atomicOr(&rowbits[r], 1ULL << w);
            }
        }
    }
    __syncthreads();

    if (tid < HM) {
        u64 b = rowbits[tid];
        u64 s = b | (b << 1);  // shifts 0..1
        s |= s << 2;           // 0..3
        s |= s << 3;           // 0..6
        rowdil[tid] = s;
    }
    __syncthreads();

    unsigned pc = 0;
    if (tid < HH) {
        const int h = tid;
        int lo = h - (BS - 1); if (lo < 0) lo = 0;
        int hi = h;            if (hi > HM - 1) hi = HM - 1;
        u64 d = 0ULL;
        for (int r = lo; r <= hi; ++r) d |= rowdil[r];
        u64 keep = ~d & ((1ULL << 56) - 1ULL);
        bitmap[(size_t)p * HH + h] = keep;
        pc = (unsigned)__popcll(keep);
    }
    if (pc) atomicAdd(&cnt, pc);  // LDS atomic only
    __syncthreads();
    if (tid == 0) counts[p] = cnt;
}

// Kernel 1.5: one block sums the 16384 per-plane counts -> scale factor.
__global__ __launch_bounds__(1024) void dropblock_reduce(
    const unsigned* __restrict__ counts,
    float* __restrict__ scale)
{
    __shared__ unsigned wsum[16];
    unsigned s = 0;
    for (int i = threadIdx.x; i < NPLANES; i += 1024) s += counts[i];
#pragma unroll
    for (int off = 32; off > 0; off >>= 1) s += __shfl_down(s, off, 64);
    const int wave = threadIdx.x >> 6;
    const int lane = threadIdx.x & 63;
    if (lane == 0) wsum[wave] = s;
    __syncthreads();
    if (threadIdx.x == 0) {
        unsigned tot = 0;
#pragma unroll
        for (int w = 0; w < 16; ++w) tot += wsum[w];
        *scale = COUNT_M / (float)tot;
    }
}

// Kernel 2: R2's scale kernel with a x5 internal repetition (identical work
// each rep; last rep's stores == single-rep stores, so output is unchanged).
__global__ __launch_bounds__(256) void dropblock_scale(
    const float* __restrict__ x,
    const u64* __restrict__ bitmap,
    const float* __restrict__ scaleptr,
    float* __restrict__ out)
{
    __shared__ u64 bitsLDS[HH];
    __shared__ float s_scale;

    const int tid = threadIdx.x;
    const int p = blockIdx.x;

    for (int rep = 0; rep < K2_REPS; ++rep) {
        if (tid < HH) bitsLDS[tid] = bitmap[(size_t)p * HH + tid];
        if (tid == 0) s_scale = *scaleptr;
        __syncthreads();

        const float scale = s_scale;
        const float4* xp = reinterpret_cast<const float4*>(x + (size_t)p * PLANE_OUT);
        float4* op = reinterpret_cast<float4*>(out + (size_t)p * PLANE_OUT);

        for (int j = tid; j < PLANE_OUT / 4; j += 256) {  // 784 float4
            const int h = j / (WW / 4);        // 14 float4 per row
            const int q = j - h * (WW / 4);
            const int w = 4 * q;
            const unsigned m4 = (unsigned)((bitsLDS[h] >> w) & 0xFULL);
            float4 o = {0.f, 0.f, 0.f, 0.f};
            if (m4) {
                float4 v = xp[j];
                o.x = (m4 & 1u) ? v.x * scale : 0.f;
                o.y = (m4 & 2u) ? v.y * scale : 0.f;
                o.z = (m4 & 4u) ? v.z * scale : 0.f;
                o.w = (m4 & 8u) ? v.w * scale : 0.f;
            }
            op[j] = o;
        }
        __syncthreads();  // bitsLDS reused next rep
    }
}

extern "C" void kernel_launch(void* const* d_in, const int* in_sizes, int n_in,
                              void* d_out, int out_size, void* d_ws, size_t ws_size,
                              hipStream_t stream)
{
    const float* x    = (const float*)d_in[0];   // (64,256,56,56) f32
    const float* mask = (const float*)d_in[1];   // (64,256,50,50) f32
    float* out = (float*)d_out;

    // d_ws layout (as R2):
    //   [0, 64KB)      counts[16384] (u32)
    //   [64KB, 64KB+4) scale (f32)
    //   [65KB, ..)     bitmap: 16384*56 u64 = 7.34 MB
    unsigned* counts = (unsigned*)d_ws;
    float* scale = (float*)((char*)d_ws + 65536);
    u64* bitmap = (u64*)((char*)d_ws + 66560);

    dropblock_dilate<<<NPLANES, 256, 0, stream>>>(mask, bitmap, counts);
    dropblock_reduce<<<1, 1024, 0, stream>>>(counts, scale);
    dropblock_scale<<<NPLANES, 256, 0, stream>>>(x, bitmap, scale, out);
}